// Round 1
// baseline (292.885 us; speedup 1.0000x reference)
//
#include <hip/hip_runtime.h>

typedef short bf16x8 __attribute__((ext_vector_type(8)));
typedef float f32x4 __attribute__((ext_vector_type(4)));
typedef unsigned short ushort8 __attribute__((ext_vector_type(8)));

#define BATCH 16
#define DCAT 512
#define CIN 256
#define COUT 256
#define HH 64
#define WW 64
#define HP 66
#define WP 66

__device__ __forceinline__ unsigned short f2bf(float f) {
  unsigned int u = __float_as_uint(f);
  unsigned int r = (u + 0x7fffu + ((u >> 16) & 1u)) >> 16;
  return (unsigned short)r;
}

// ---------------- style MLP: s = lrelu(lrelu(lrelu(y@w0.T+b0)@w1.T+b1)@w2.T+b2)
__global__ void style_mlp(const float* __restrict__ y,
                          const float* __restrict__ w0, const float* __restrict__ b0,
                          const float* __restrict__ w1, const float* __restrict__ b1,
                          const float* __restrict__ w2, const float* __restrict__ b2,
                          float* __restrict__ s_out) {
  int b = blockIdx.x;
  int c = threadIdx.x;  // 256 threads
  __shared__ float yb[DCAT];
  __shared__ float t[CIN];
  for (int i = c; i < DCAT; i += CIN) yb[i] = y[b * DCAT + i];
  __syncthreads();
  float a = b0[c];
  const float* wr = w0 + c * DCAT;
  for (int d = 0; d < DCAT; d++) a += yb[d] * wr[d];
  a = a >= 0.f ? a : 0.01f * a;
  t[c] = a;
  __syncthreads();
  float a1 = b1[c];
  const float* wr1 = w1 + c * CIN;
  for (int d = 0; d < CIN; d++) a1 += t[d] * wr1[d];
  a1 = a1 >= 0.f ? a1 : 0.01f * a1;
  __syncthreads();
  t[c] = a1;
  __syncthreads();
  float a2 = b2[c];
  const float* wr2 = w2 + c * CIN;
  for (int d = 0; d < CIN; d++) a2 += t[d] * wr2[d];
  a2 = a2 >= 0.f ? a2 : 0.01f * a2;
  s_out[b * CIN + c] = a2;
}

// ---------------- weight transpose: conv_w(O,I,3,3) fp32 -> wt[tap][o][i] bf16
__global__ void prep_w(const float* __restrict__ cw, unsigned short* __restrict__ wt) {
  int idx = blockIdx.x * 256 + threadIdx.x;  // o*256 + i
  int o = idx >> 8, i = idx & 255;
  const float* p = cw + idx * 9;
#pragma unroll
  for (int t = 0; t < 9; t++) wt[((size_t)(t * COUT + o)) * CIN + i] = f2bf(p[t]);
}

// ---------------- padded, scaled, c8-blocked bf16 activation:
// xpad[b][c8][hh][ww][8]  (hh,ww in [0,66), zero border)
__global__ void prep_x(const float* __restrict__ x, const float* __restrict__ s,
                       unsigned short* __restrict__ xpad) {
  int blk = blockIdx.x;        // 16*32 blocks
  int b = blk >> 5, c8 = blk & 31;
  float sv[8];
#pragma unroll
  for (int j = 0; j < 8; j++) sv[j] = s[b * CIN + c8 * 8 + j];
  const float* xb = x + ((size_t)(b * CIN + c8 * 8)) * (HH * WW);
  unsigned short* xp = xpad + ((size_t)(b * 32 + c8)) * (HP * WP * 8);
  for (int pp = threadIdx.x; pp < HP * WP; pp += 256) {
    int hh = pp / WP, ww = pp - hh * WP;
    ushort8 o = {0, 0, 0, 0, 0, 0, 0, 0};
    if (hh >= 1 && hh <= HH && ww >= 1 && ww <= WW) {
      int base = (hh - 1) * WW + (ww - 1);
#pragma unroll
      for (int j = 0; j < 8; j++) o[j] = f2bf(xb[j * (HH * WW) + base] * sv[j]);
    }
    *(ushort8*)(xp + (size_t)pp * 8) = o;
  }
}

// ---------------- implicit-GEMM conv: M=B*H*W pixels, N=COUT, K=9*CIN
__device__ __forceinline__ void gl2lds16(const void* g, void* l) {
  __builtin_amdgcn_global_load_lds((const __attribute__((address_space(1))) void*)g,
                                   (__attribute__((address_space(3))) void*)l, 16, 0, 0);
}

__global__ void __launch_bounds__(256) gemm_conv(const unsigned short* __restrict__ xpad,
                                                 const unsigned short* __restrict__ wt,
                                                 float* __restrict__ out) {
  __shared__ unsigned short As[128 * 32];  // [pixel][k32] bf16, 64B rows
  __shared__ unsigned short Bs[128 * 32];  // [o][k32] bf16 (B^T layout)
  int tid = threadIdx.x;
  int wid = tid >> 6, lane = tid & 63;
  int bid = blockIdx.x;
  int n_t = bid & 1, m_t = bid >> 1;  // n fastest: both N-tiles of an M-tile adjacent
  int m0 = m_t << 7;                  // first global pixel of tile (never crosses batch)
  int b = m0 >> 12;
  int h0 = (m0 >> 6) & 63;            // tile covers image rows h0, h0+1
  int pq = lane >> 2;                 // 0..15 : pixel/o within a 16-row load group
  int kq = lane & 3;                  // 0..3  : 8-channel chunk within BK=32
  int wm = wid & 1, wn = wid >> 1;    // 2x2 wave grid, each wave 64x64

  f32x4 acc[4][4];
#pragma unroll
  for (int mi = 0; mi < 4; mi++)
#pragma unroll
    for (int ni = 0; ni < 4; ni++) acc[mi][ni] = (f32x4){0.f, 0.f, 0.f, 0.f};

  int pA0 = wid * 32 + pq;            // local pixel for A load 0 (load 1: +16)
  int oG0 = n_t * 128 + wid * 32 + pq;  // global o for B load 0
  unsigned short* ldsA0 = As + (wid * 32) * 32;
  unsigned short* ldsA1 = As + (wid * 32 + 16) * 32;
  unsigned short* ldsB0 = Bs + (wid * 32) * 32;
  unsigned short* ldsB1 = Bs + (wid * 32 + 16) * 32;

  const unsigned short* fa = As + (wm * 64 + (lane & 15)) * 32 + (lane >> 4) * 8;
  const unsigned short* fb = Bs + (wn * 64 + (lane & 15)) * 32 + (lane >> 4) * 8;

  for (int kk = 0; kk < 72; kk++) {   // K = 9 taps * 8 chunks of 32
    int tap = kk >> 3;
    int kc = kk & 7;
    int kh = tap / 3;
    int kw = tap - kh * 3;
    int c8 = kc * 4 + kq;
    // --- A staging (2 rows x 64 px x 32 ch from padded tensor; tap = pure shift)
    {
      int hh = h0 + (pA0 >> 6) + kh;
      int wc = (pA0 & 63) + kw;
      const unsigned short* ga =
          xpad + (((size_t)((b * 32 + c8) * HP + hh)) * WP + wc) * 8;
      gl2lds16(ga, ldsA0);
      int p1 = pA0 + 16;
      int hh1 = h0 + (p1 >> 6) + kh;
      int wc1 = (p1 & 63) + kw;
      const unsigned short* ga1 =
          xpad + (((size_t)((b * 32 + c8) * HP + hh1)) * WP + wc1) * 8;
      gl2lds16(ga1, ldsA1);
    }
    // --- B staging
    {
      const unsigned short* gb =
          wt + ((size_t)(tap * COUT + oG0)) * CIN + kc * 32 + kq * 8;
      gl2lds16(gb, ldsB0);
      gl2lds16(gb + 16 * CIN, ldsB1);
    }
    __syncthreads();
    bf16x8 av[4], bv[4];
#pragma unroll
    for (int mi = 0; mi < 4; mi++) av[mi] = *(const bf16x8*)(fa + mi * 16 * 32);
#pragma unroll
    for (int ni = 0; ni < 4; ni++) bv[ni] = *(const bf16x8*)(fb + ni * 16 * 32);
#pragma unroll
    for (int mi = 0; mi < 4; mi++)
#pragma unroll
      for (int ni = 0; ni < 4; ni++)
        acc[mi][ni] =
            __builtin_amdgcn_mfma_f32_16x16x32_bf16(av[mi], bv[ni], acc[mi][ni], 0, 0, 0);
    __syncthreads();
  }

  // ---- epilogue: D row = pixel (quad*4+reg), col = o (lane&15); 4 consecutive
  // pixels per lane -> aligned float4 store.
  int pixbase = m0 & 4095;
  int quad = lane >> 4;
  int col = lane & 15;
#pragma unroll
  for (int mi = 0; mi < 4; mi++) {
    int pm = pixbase + wm * 64 + mi * 16 + quad * 4;
#pragma unroll
    for (int ni = 0; ni < 4; ni++) {
      int on = n_t * 128 + wn * 64 + ni * 16 + col;
      float* op = out + ((size_t)(b * COUT + on) << 12) + pm;
      *(f32x4*)op = acc[mi][ni];
    }
  }
}

extern "C" void kernel_launch(void* const* d_in, const int* in_sizes, int n_in,
                              void* d_out, int out_size, void* d_ws, size_t ws_size,
                              hipStream_t stream) {
  const float* x = (const float*)d_in[0];
  const float* y = (const float*)d_in[1];
  const float* w0 = (const float*)d_in[2];
  const float* b0 = (const float*)d_in[3];
  const float* w1 = (const float*)d_in[4];
  const float* b1 = (const float*)d_in[5];
  const float* w2 = (const float*)d_in[6];
  const float* b2 = (const float*)d_in[7];
  const float* cw = (const float*)d_in[8];
  float* out = (float*)d_out;

  // workspace layout: s (16 KiB) | wt bf16 (1.125 MiB) | xpad bf16 (~34 MiB)
  char* ws = (char*)d_ws;
  float* s = (float*)ws;
  unsigned short* wt = (unsigned short*)(ws + 16384);
  unsigned short* xpad = (unsigned short*)(ws + 16384 + 9 * COUT * CIN * 2);

  style_mlp<<<BATCH, 256, 0, stream>>>(y, w0, b0, w1, b1, w2, b2, s);
  prep_w<<<(COUT * CIN) / 256, 256, 0, stream>>>(cw, wt);
  prep_x<<<BATCH * 32, 256, 0, stream>>>(x, s, xpad);
  gemm_conv<<<(BATCH * HH * WW / 128) * 2, 256, 0, stream>>>(xpad, wt, out);
}

// Round 2
// 268.947 us; speedup vs baseline: 1.0890x; 1.0890x over previous
//
#include <hip/hip_runtime.h>

typedef short bf16x8 __attribute__((ext_vector_type(8)));
typedef float f32x4 __attribute__((ext_vector_type(4)));
typedef unsigned short ushort8 __attribute__((ext_vector_type(8)));

#define BATCH 16
#define DCAT 512
#define CIN 256
#define COUT 256
#define HH 64
#define WW 64
#define HP 66
#define WP 66
#define PLANE (HP * WP * 8)  // shorts per c8-plane

__device__ __forceinline__ unsigned short f2bf(float f) {
  unsigned int u = __float_as_uint(f);
  unsigned int r = (u + 0x7fffu + ((u >> 16) & 1u)) >> 16;
  return (unsigned short)r;
}

// ---------------- style MLP: LDS-tiled, coalesced weight reads
__global__ void style_mlp(const float* __restrict__ y,
                          const float* __restrict__ w0, const float* __restrict__ b0,
                          const float* __restrict__ w1, const float* __restrict__ b1,
                          const float* __restrict__ w2, const float* __restrict__ b2,
                          float* __restrict__ s_out) {
  int b = blockIdx.x;
  int c = threadIdx.x;  // 256 threads
  __shared__ float yb[DCAT];
  __shared__ float t[CIN];
  __shared__ float wtile[CIN * 65];  // +1 pad per 64-col row -> conflict-free
  for (int i = c; i < DCAT; i += CIN) yb[i] = y[b * DCAT + i];
  __syncthreads();

  // layer 0: 512 -> 256
  float a = b0[c];
  for (int d0 = 0; d0 < DCAT; d0 += 64) {
#pragma unroll
    for (int i = 0; i < 16; i++) {  // 256x64 tile as float4, coalesced
      int cc = i * 16 + (c >> 4);
      int dd = (c & 15) * 4;
      f32x4 v = *(const f32x4*)(w0 + cc * DCAT + d0 + dd);
      wtile[cc * 65 + dd + 0] = v[0];
      wtile[cc * 65 + dd + 1] = v[1];
      wtile[cc * 65 + dd + 2] = v[2];
      wtile[cc * 65 + dd + 3] = v[3];
    }
    __syncthreads();
#pragma unroll
    for (int dd = 0; dd < 64; dd++) a += yb[d0 + dd] * wtile[c * 65 + dd];
    __syncthreads();
  }
  a = a >= 0.f ? a : 0.01f * a;
  t[c] = a;
  __syncthreads();

  // layers 1,2: 256 -> 256
  const float* ws[2] = {w1, w2};
  const float* bs[2] = {b1, b2};
  for (int L = 0; L < 2; L++) {
    float acc = bs[L][c];
    const float* wl = ws[L];
    for (int d0 = 0; d0 < CIN; d0 += 64) {
#pragma unroll
      for (int i = 0; i < 16; i++) {
        int cc = i * 16 + (c >> 4);
        int dd = (c & 15) * 4;
        f32x4 v = *(const f32x4*)(wl + cc * CIN + d0 + dd);
        wtile[cc * 65 + dd + 0] = v[0];
        wtile[cc * 65 + dd + 1] = v[1];
        wtile[cc * 65 + dd + 2] = v[2];
        wtile[cc * 65 + dd + 3] = v[3];
      }
      __syncthreads();
#pragma unroll
      for (int dd = 0; dd < 64; dd++) acc += t[d0 + dd] * wtile[c * 65 + dd];
      __syncthreads();
    }
    acc = acc >= 0.f ? acc : 0.01f * acc;
    if (L == 0) {
      t[c] = acc;
      __syncthreads();
    } else {
      s_out[b * CIN + c] = acc;
    }
  }
}

// ---------------- weight transpose: conv_w(O,I,3,3) fp32 -> wt[tap][o][i] bf16
__global__ void prep_w(const float* __restrict__ cw, unsigned short* __restrict__ wt) {
  int idx = blockIdx.x * 256 + threadIdx.x;  // o*256 + i
  const float* p = cw + idx * 9;
  int o = idx >> 8, i = idx & 255;
#pragma unroll
  for (int t = 0; t < 9; t++) wt[((size_t)(t * COUT + o)) * CIN + i] = f2bf(p[t]);
}

// ---------------- padded, scaled, c8-blocked bf16 activation:
// xpad[b][c8][hh][ww][8]  (hh,ww in [0,66), zero border)
__global__ void prep_x(const float* __restrict__ x, const float* __restrict__ s,
                       unsigned short* __restrict__ xpad) {
  int blk = blockIdx.x;  // 16*32 blocks
  int b = blk >> 5, c8 = blk & 31;
  int tid = threadIdx.x;
  float sv[8];
#pragma unroll
  for (int j = 0; j < 8; j++) sv[j] = s[b * CIN + c8 * 8 + j];
  const float* xb = x + ((size_t)(b * CIN + c8 * 8)) * (HH * WW);
  unsigned short* xp = xpad + ((size_t)(b * 32 + c8)) * PLANE;

  // zero border (260 px)
  ushort8 z = {0, 0, 0, 0, 0, 0, 0, 0};
  for (int i = tid; i < 260; i += 256) {
    int hh, ww;
    if (i < 66) { hh = 0; ww = i; }
    else if (i < 132) { hh = 65; ww = i - 66; }
    else if (i < 196) { hh = i - 132 + 1; ww = 0; }
    else { hh = i - 196 + 1; ww = 65; }
    *(ushort8*)(xp + (hh * WP + ww) * 8) = z;
  }
  // interior: 4 px per thread, float4 reads, 64B stores
  for (int g = tid; g < 1024; g += 256) {
    int hh = (g >> 4) + 1;
    int w0 = (g & 15) * 4 + 1;
    int base = (hh - 1) * WW + (w0 - 1);
    f32x4 v[8];
#pragma unroll
    for (int j = 0; j < 8; j++) v[j] = *(const f32x4*)(xb + j * (HH * WW) + base);
    unsigned short* op = xp + (hh * WP + w0) * 8;
#pragma unroll
    for (int t2 = 0; t2 < 4; t2++) {
      ushort8 o;
#pragma unroll
      for (int j = 0; j < 8; j++) o[j] = f2bf(v[j][t2] * sv[j]);
      *(ushort8*)(op + t2 * 8) = o;
    }
  }
}

// ---------------- implicit-GEMM conv: BM=128 px, BN=256 out, BK=64
__device__ __forceinline__ void gl2lds16(const void* g, void* l) {
  __builtin_amdgcn_global_load_lds((const __attribute__((address_space(1))) void*)g,
                                   (__attribute__((address_space(3))) void*)l, 16, 0, 0);
}

__global__ void __launch_bounds__(512, 4) gemm_conv(const unsigned short* __restrict__ xpad,
                                                    const unsigned short* __restrict__ wt,
                                                    float* __restrict__ out) {
  __shared__ unsigned short As[128 * 64];  // [pixel][64ch], 128B rows, XOR-swizzled chunks
  __shared__ unsigned short Bs[256 * 64];  // [o][64ch]
  int tid = threadIdx.x;
  int wid = tid >> 6, lane = tid & 63;
  int m_t = blockIdx.x;              // 512 blocks
  int m0 = m_t << 7;
  int b = m0 >> 12;
  int h0 = (m0 >> 6) & 63;           // tile covers image rows h0, h0+1
  int wm = wid & 1, wn = wid >> 1;   // 2x4 wave grid, each wave 64x64

  f32x4 acc[4][4];
#pragma unroll
  for (int mi = 0; mi < 4; mi++)
#pragma unroll
    for (int ni = 0; ni < 4; ni++) acc[mi][ni] = (f32x4){0.f, 0.f, 0.f, 0.f};

  // ---- stager lane invariants (global lane id = tid)
  int p = tid >> 3;                  // pixel 0..63 (round 1: +64 -> next image row)
  int cs = tid & 7;                  // chunk slot in LDS row
  int gsA = cs ^ (p & 7);            // XOR swizzle: LDS slot cs holds global chunk gsA
  const unsigned short* aL =
      xpad + ((size_t)((b * 32 + gsA) * HP + h0)) * (WP * 8) + p * 8;
  int o_l = tid >> 3;                // o 0..63 within a 64-row round
  const unsigned short* bL = wt + o_l * CIN + (cs ^ (o_l & 7)) * 8;

  char* As_w0 = (char*)As + wid * 1024;
  char* As_w1 = (char*)As + 8192 + wid * 1024;
  char* Bs_w0 = (char*)Bs + wid * 1024;
  char* Bs_w1 = (char*)Bs + 8192 + wid * 1024;
  char* Bs_w2 = (char*)Bs + 16384 + wid * 1024;
  char* Bs_w3 = (char*)Bs + 24576 + wid * 1024;

  // ---- reader frag offsets (bytes into As/Bs), XOR-unswizzled
  int rA = wm * 64 + (lane & 15);
  int rB = wn * 64 + (lane & 15);
  int qa = lane >> 4;
  int offA0 = rA * 128 + ((qa ^ (rA & 7)) * 16);
  int offA1 = rA * 128 + (((qa + 4) ^ (rA & 7)) * 16);
  int offB0 = rB * 128 + ((qa ^ (rB & 7)) * 16);
  int offB1 = rB * 128 + (((qa + 4) ^ (rB & 7)) * 16);

  for (int kh = 0; kh < 3; kh++) {
    for (int kw = 0; kw < 3; kw++) {
      const unsigned short* aT = aL + (kh * WP + kw) * 8;
      const unsigned short* bT = bL + (kh * 3 + kw) * (COUT * CIN);
#pragma unroll
      for (int kc2 = 0; kc2 < 4; kc2++) {
        const unsigned short* aG = aT + kc2 * (8 * PLANE);
        const unsigned short* bG = bT + kc2 * 64;
        gl2lds16(aG, As_w0);
        gl2lds16(aG + WP * 8, As_w1);
        gl2lds16(bG, Bs_w0);
        gl2lds16(bG + 64 * CIN, Bs_w1);
        gl2lds16(bG + 128 * CIN, Bs_w2);
        gl2lds16(bG + 192 * CIN, Bs_w3);
        __syncthreads();
#pragma unroll
        for (int kb = 0; kb < 2; kb++) {
          int oa = kb ? offA1 : offA0;
          int ob = kb ? offB1 : offB0;
          bf16x8 av[4], bv[4];
#pragma unroll
          for (int mi = 0; mi < 4; mi++)
            av[mi] = *(const bf16x8*)((const char*)As + oa + mi * 2048);
#pragma unroll
          for (int ni = 0; ni < 4; ni++)
            bv[ni] = *(const bf16x8*)((const char*)Bs + ob + ni * 2048);
#pragma unroll
          for (int mi = 0; mi < 4; mi++)
#pragma unroll
            for (int ni = 0; ni < 4; ni++)
              acc[mi][ni] = __builtin_amdgcn_mfma_f32_16x16x32_bf16(av[mi], bv[ni],
                                                                    acc[mi][ni], 0, 0, 0);
        }
        __syncthreads();
      }
    }
  }

  // ---- epilogue: D row = pixel (quad*4+reg), col = o (lane&15)
  int pixbase = m0 & 4095;
  int quad = lane >> 4;
  int col = lane & 15;
#pragma unroll
  for (int mi = 0; mi < 4; mi++) {
    int pm = pixbase + wm * 64 + mi * 16 + quad * 4;
#pragma unroll
    for (int ni = 0; ni < 4; ni++) {
      int on = wn * 64 + ni * 16 + col;
      float* op = out + ((size_t)(b * COUT + on) << 12) + pm;
      *(f32x4*)op = acc[mi][ni];
    }
  }
}

extern "C" void kernel_launch(void* const* d_in, const int* in_sizes, int n_in,
                              void* d_out, int out_size, void* d_ws, size_t ws_size,
                              hipStream_t stream) {
  const float* x = (const float*)d_in[0];
  const float* y = (const float*)d_in[1];
  const float* w0 = (const float*)d_in[2];
  const float* b0 = (const float*)d_in[3];
  const float* w1 = (const float*)d_in[4];
  const float* b1 = (const float*)d_in[5];
  const float* w2 = (const float*)d_in[6];
  const float* b2 = (const float*)d_in[7];
  const float* cw = (const float*)d_in[8];
  float* out = (float*)d_out;

  // workspace: s (16 KiB) | wt bf16 (1.125 MiB) | xpad bf16 (~35.7 MiB)
  char* ws = (char*)d_ws;
  float* s = (float*)ws;
  unsigned short* wt = (unsigned short*)(ws + 16384);
  unsigned short* xpad = (unsigned short*)(ws + 16384 + 9 * COUT * CIN * 2);

  style_mlp<<<BATCH, 256, 0, stream>>>(y, w0, b0, w1, b1, w2, b2, s);
  prep_w<<<(COUT * CIN) / 256, 256, 0, stream>>>(cw, wt);
  prep_x<<<BATCH * 32, 256, 0, stream>>>(x, s, xpad);
  gemm_conv<<<BATCH * HH * WW / 128, 512, 0, stream>>>(xpad, wt, out);
}

// Round 3
// 214.189 us; speedup vs baseline: 1.3674x; 1.2557x over previous
//
#include <hip/hip_runtime.h>

typedef short bf16x8 __attribute__((ext_vector_type(8)));
typedef float f32x4 __attribute__((ext_vector_type(4)));
typedef unsigned short ushort8 __attribute__((ext_vector_type(8)));
typedef unsigned short ushort4v __attribute__((ext_vector_type(4)));

#define BATCH 16
#define DCAT 512
#define CIN 256
#define COUT 256
#define HH 64
#define WW 64
#define HP 66
#define WP 66
#define PLANE (HP * WP * 8)  // shorts per c8-plane

__device__ __forceinline__ unsigned short f2bf(float f) {
  unsigned int u = __float_as_uint(f);
  unsigned int r = (u + 0x7fffu + ((u >> 16) & 1u)) >> 16;
  return (unsigned short)r;
}

// ---------------- MLP layer: one wave per output element (b,c).
// Coalesced weight-row reads + 64-lane butterfly reduction.
template <int IN_DIM>
__global__ void __launch_bounds__(256) mlp_layer(const float* __restrict__ in,
                                                 const float* __restrict__ w,
                                                 const float* __restrict__ bias,
                                                 float* __restrict__ out) {
  int wid = threadIdx.x >> 6, lane = threadIdx.x & 63;
  int oidx = blockIdx.x * 4 + wid;  // (b<<8)|c
  int b = oidx >> 8, c = oidx & 255;
  const float* wr = w + (size_t)c * IN_DIM;
  const float* ir = in + (size_t)b * IN_DIM;
  float sum = 0.f;
#pragma unroll
  for (int d0 = 0; d0 < IN_DIM; d0 += 256) {
    f32x4 wv = *(const f32x4*)(wr + d0 + lane * 4);
    f32x4 iv = *(const f32x4*)(ir + d0 + lane * 4);
    sum += wv[0] * iv[0] + wv[1] * iv[1] + wv[2] * iv[2] + wv[3] * iv[3];
  }
#pragma unroll
  for (int off = 32; off; off >>= 1) sum += __shfl_xor(sum, off, 64);
  if (lane == 0) {
    float a = sum + bias[c];
    out[oidx] = a >= 0.f ? a : 0.01f * a;
  }
}

// ---------------- weight transpose: conv_w(O,I,3,3) fp32 -> wt[tap][o][i] bf16
// thread = (tap, o, i4): contiguous ushort4 stores (128B/wave), strided reads hit L2.
__global__ void prep_w(const float* __restrict__ cw, unsigned short* __restrict__ wt) {
  int idx = blockIdx.x * 256 + threadIdx.x;  // 9*256*64 = 147456 threads
  int t = idx / 16384;
  int r = idx - t * 16384;  // o*64 + i4
  int o = r >> 6, i4 = r & 63;
  ushort4v v;
#pragma unroll
  for (int j = 0; j < 4; j++) v[j] = f2bf(cw[(o * 256 + i4 * 4 + j) * 9 + t]);
  *(ushort4v*)(wt + ((size_t)(t * COUT + o)) * CIN + i4 * 4) = v;
}

// ---------------- padded, scaled, c8-blocked bf16 activation:
// xpad[b][c8][hh][ww][8]  (hh,ww in [0,66), zero border)
__global__ void prep_x(const float* __restrict__ x, const float* __restrict__ s,
                       unsigned short* __restrict__ xpad) {
  int blk = blockIdx.x;  // 16*32 blocks
  int b = blk >> 5, c8 = blk & 31;
  int tid = threadIdx.x;
  float sv[8];
#pragma unroll
  for (int j = 0; j < 8; j++) sv[j] = s[b * CIN + c8 * 8 + j];
  const float* xb = x + ((size_t)(b * CIN + c8 * 8)) * (HH * WW);
  unsigned short* xp = xpad + ((size_t)(b * 32 + c8)) * PLANE;

  // zero border (260 px)
  ushort8 z = {0, 0, 0, 0, 0, 0, 0, 0};
  for (int i = tid; i < 260; i += 256) {
    int hh, ww;
    if (i < 66) { hh = 0; ww = i; }
    else if (i < 132) { hh = 65; ww = i - 66; }
    else if (i < 196) { hh = i - 132 + 1; ww = 0; }
    else { hh = i - 196 + 1; ww = 65; }
    *(ushort8*)(xp + (hh * WP + ww) * 8) = z;
  }
  // interior: 4 px per thread, float4 reads, 64B stores
  for (int g = tid; g < 1024; g += 256) {
    int hh = (g >> 4) + 1;
    int w0 = (g & 15) * 4 + 1;
    int base = (hh - 1) * WW + (w0 - 1);
    f32x4 v[8];
#pragma unroll
    for (int j = 0; j < 8; j++) v[j] = *(const f32x4*)(xb + j * (HH * WW) + base);
    unsigned short* op = xp + (hh * WP + w0) * 8;
#pragma unroll
    for (int t2 = 0; t2 < 4; t2++) {
      ushort8 o;
#pragma unroll
      for (int j = 0; j < 8; j++) o[j] = f2bf(v[j][t2] * sv[j]);
      *(ushort8*)(op + t2 * 8) = o;
    }
  }
}

// ---------------- implicit-GEMM conv: BM=128 px, BN=256 out, BK=64
__device__ __forceinline__ void gl2lds16(const void* g, void* l) {
  __builtin_amdgcn_global_load_lds((const __attribute__((address_space(1))) void*)g,
                                   (__attribute__((address_space(3))) void*)l, 16, 0, 0);
}

__global__ void __launch_bounds__(512, 4) gemm_conv(const unsigned short* __restrict__ xpad,
                                                    const unsigned short* __restrict__ wt,
                                                    float* __restrict__ out) {
  __shared__ unsigned short As[128 * 64];  // [pixel][64ch], 128B rows, XOR-swizzled chunks
  __shared__ unsigned short Bs[256 * 64];  // [o][64ch]
  int tid = threadIdx.x;
  int wid = tid >> 6, lane = tid & 63;
  int m_t = blockIdx.x;              // 512 blocks
  int m0 = m_t << 7;
  int b = m0 >> 12;
  int h0 = (m0 >> 6) & 63;           // tile covers image rows h0, h0+1
  int wm = wid & 1, wn = wid >> 1;   // 2x4 wave grid, each wave 64x64

  f32x4 acc[4][4];
#pragma unroll
  for (int mi = 0; mi < 4; mi++)
#pragma unroll
    for (int ni = 0; ni < 4; ni++) acc[mi][ni] = (f32x4){0.f, 0.f, 0.f, 0.f};

  // ---- stager lane invariants (global lane id = tid)
  int p = tid >> 3;                  // pixel 0..63 (round 1: +64 -> next image row)
  int cs = tid & 7;                  // chunk slot in LDS row
  int gsA = cs ^ (p & 7);            // XOR swizzle: LDS slot cs holds global chunk gsA
  const unsigned short* aL =
      xpad + ((size_t)((b * 32 + gsA) * HP + h0)) * (WP * 8) + p * 8;
  int o_l = tid >> 3;                // o 0..63 within a 64-row round
  const unsigned short* bL = wt + o_l * CIN + (cs ^ (o_l & 7)) * 8;

  char* As_w0 = (char*)As + wid * 1024;
  char* As_w1 = (char*)As + 8192 + wid * 1024;
  char* Bs_w0 = (char*)Bs + wid * 1024;
  char* Bs_w1 = (char*)Bs + 8192 + wid * 1024;
  char* Bs_w2 = (char*)Bs + 16384 + wid * 1024;
  char* Bs_w3 = (char*)Bs + 24576 + wid * 1024;

  // ---- reader frag offsets (bytes into As/Bs), XOR-unswizzled
  int rA = wm * 64 + (lane & 15);
  int rB = wn * 64 + (lane & 15);
  int qa = lane >> 4;
  int offA0 = rA * 128 + ((qa ^ (rA & 7)) * 16);
  int offA1 = rA * 128 + (((qa + 4) ^ (rA & 7)) * 16);
  int offB0 = rB * 128 + ((qa ^ (rB & 7)) * 16);
  int offB1 = rB * 128 + (((qa + 4) ^ (rB & 7)) * 16);

  for (int kh = 0; kh < 3; kh++) {
    for (int kw = 0; kw < 3; kw++) {
      const unsigned short* aT = aL + (kh * WP + kw) * 8;
      const unsigned short* bT = bL + (kh * 3 + kw) * (COUT * CIN);
#pragma unroll
      for (int kc2 = 0; kc2 < 4; kc2++) {
        const unsigned short* aG = aT + kc2 * (8 * PLANE);
        const unsigned short* bG = bT + kc2 * 64;
        gl2lds16(aG, As_w0);
        gl2lds16(aG + WP * 8, As_w1);
        gl2lds16(bG, Bs_w0);
        gl2lds16(bG + 64 * CIN, Bs_w1);
        gl2lds16(bG + 128 * CIN, Bs_w2);
        gl2lds16(bG + 192 * CIN, Bs_w3);
        __syncthreads();
#pragma unroll
        for (int kb = 0; kb < 2; kb++) {
          int oa = kb ? offA1 : offA0;
          int ob = kb ? offB1 : offB0;
          bf16x8 av[4], bv[4];
#pragma unroll
          for (int mi = 0; mi < 4; mi++)
            av[mi] = *(const bf16x8*)((const char*)As + oa + mi * 2048);
#pragma unroll
          for (int ni = 0; ni < 4; ni++)
            bv[ni] = *(const bf16x8*)((const char*)Bs + ob + ni * 2048);
#pragma unroll
          for (int mi = 0; mi < 4; mi++)
#pragma unroll
            for (int ni = 0; ni < 4; ni++)
              acc[mi][ni] = __builtin_amdgcn_mfma_f32_16x16x32_bf16(av[mi], bv[ni],
                                                                    acc[mi][ni], 0, 0, 0);
        }
        __syncthreads();
      }
    }
  }

  // ---- epilogue: D row = pixel (quad*4+reg), col = o (lane&15)
  int pixbase = m0 & 4095;
  int quad = lane >> 4;
  int col = lane & 15;
#pragma unroll
  for (int mi = 0; mi < 4; mi++) {
    int pm = pixbase + wm * 64 + mi * 16 + quad * 4;
#pragma unroll
    for (int ni = 0; ni < 4; ni++) {
      int on = wn * 64 + ni * 16 + col;
      float* op = out + ((size_t)(b * COUT + on) << 12) + pm;
      *(f32x4*)op = acc[mi][ni];
    }
  }
}

extern "C" void kernel_launch(void* const* d_in, const int* in_sizes, int n_in,
                              void* d_out, int out_size, void* d_ws, size_t ws_size,
                              hipStream_t stream) {
  const float* x = (const float*)d_in[0];
  const float* y = (const float*)d_in[1];
  const float* w0 = (const float*)d_in[2];
  const float* b0 = (const float*)d_in[3];
  const float* w1 = (const float*)d_in[4];
  const float* b1 = (const float*)d_in[5];
  const float* w2 = (const float*)d_in[6];
  const float* b2 = (const float*)d_in[7];
  const float* cw = (const float*)d_in[8];
  float* out = (float*)d_out;

  // workspace: t0 | t1 | s | wt bf16 | xpad bf16
  char* ws = (char*)d_ws;
  float* t0 = (float*)ws;                       // 16 KiB
  float* t1 = (float*)(ws + 16384);             // 16 KiB
  float* s = (float*)(ws + 32768);              // 16 KiB
  unsigned short* wt = (unsigned short*)(ws + 49152);  // 1.125 MiB
  unsigned short* xpad = (unsigned short*)(ws + 49152 + 9 * COUT * CIN * 2);

  mlp_layer<DCAT><<<BATCH * CIN / 4, 256, 0, stream>>>(y, w0, b0, t0);
  mlp_layer<CIN><<<BATCH * CIN / 4, 256, 0, stream>>>(t0, w1, b1, t1);
  mlp_layer<CIN><<<BATCH * CIN / 4, 256, 0, stream>>>(t1, w2, b2, s);
  prep_w<<<9 * COUT * CIN / 4 / 256, 256, 0, stream>>>(cw, wt);
  prep_x<<<BATCH * 32, 256, 0, stream>>>(x, s, xpad);
  gemm_conv<<<BATCH * HH * WW / 128, 512, 0, stream>>>(xpad, wt, out);
}

// Round 4
// 213.488 us; speedup vs baseline: 1.3719x; 1.0033x over previous
//
#include <hip/hip_runtime.h>

typedef short bf16x8 __attribute__((ext_vector_type(8)));
typedef float f32x4 __attribute__((ext_vector_type(4)));
typedef unsigned short ushort8 __attribute__((ext_vector_type(8)));
typedef unsigned short ushort4v __attribute__((ext_vector_type(4)));

#define BATCH 16
#define DCAT 512
#define CIN 256
#define COUT 256
#define HH 64
#define WW 64
#define HP 66
#define WP 66
#define PLANE (HP * WP * 8)  // shorts per c8-plane

__device__ __forceinline__ unsigned short f2bf(float f) {
  unsigned int u = __float_as_uint(f);
  unsigned int r = (u + 0x7fffu + ((u >> 16) & 1u)) >> 16;
  return (unsigned short)r;
}

// ---------------- MLP layer: one wave per output element (b,c).
template <int IN_DIM>
__global__ void __launch_bounds__(256) mlp_layer(const float* __restrict__ in,
                                                 const float* __restrict__ w,
                                                 const float* __restrict__ bias,
                                                 float* __restrict__ out) {
  int wid = threadIdx.x >> 6, lane = threadIdx.x & 63;
  int oidx = blockIdx.x * 4 + wid;  // (b<<8)|c
  int b = oidx >> 8, c = oidx & 255;
  const float* wr = w + (size_t)c * IN_DIM;
  const float* ir = in + (size_t)b * IN_DIM;
  float sum = 0.f;
#pragma unroll
  for (int d0 = 0; d0 < IN_DIM; d0 += 256) {
    f32x4 wv = *(const f32x4*)(wr + d0 + lane * 4);
    f32x4 iv = *(const f32x4*)(ir + d0 + lane * 4);
    sum += wv[0] * iv[0] + wv[1] * iv[1] + wv[2] * iv[2] + wv[3] * iv[3];
  }
#pragma unroll
  for (int off = 32; off; off >>= 1) sum += __shfl_xor(sum, off, 64);
  if (lane == 0) {
    float a = sum + bias[c];
    out[oidx] = a >= 0.f ? a : 0.01f * a;
  }
}

// ---------------- weight transpose: conv_w(O,I,3,3) fp32 -> wt[tap][o][i] bf16
__global__ void prep_w(const float* __restrict__ cw, unsigned short* __restrict__ wt) {
  int idx = blockIdx.x * 256 + threadIdx.x;  // 9*256*64 = 147456 threads
  int t = idx / 16384;
  int r = idx - t * 16384;  // o*64 + i4
  int o = r >> 6, i4 = r & 63;
  ushort4v v;
#pragma unroll
  for (int j = 0; j < 4; j++) v[j] = f2bf(cw[(o * 256 + i4 * 4 + j) * 9 + t]);
  *(ushort4v*)(wt + ((size_t)(t * COUT + o)) * CIN + i4 * 4) = v;
}

// ---------------- fused: MLP layer 3 (per-block, redundant per quarter) + padded,
// scaled, c8-blocked bf16 activation. 2048 blocks = (b, c8, row-quarter).
// MLP depends only on t1; x loads are issued first to hide their latency.
__global__ void __launch_bounds__(256) mlp3_prep_x(const float* __restrict__ t1,
                                                   const float* __restrict__ w2,
                                                   const float* __restrict__ b2,
                                                   const float* __restrict__ x,
                                                   unsigned short* __restrict__ xpad) {
  int blk = blockIdx.x;  // ((b*32 + c8)<<2) | q
  int q = blk & 3, c8 = (blk >> 2) & 31, b = blk >> 7;
  int tid = threadIdx.x;
  int wid = tid >> 6, lane = tid & 63;

  // ---- issue x loads early (independent of s): 4 px per thread, 16 rows/quarter
  int gg = q * 256 + tid;             // interior px-group: hh=(gg>>4)+1, w0=(gg&15)*4+1
  int hh = (gg >> 4) + 1;
  int w0 = (gg & 15) * 4 + 1;
  int base = (hh - 1) * WW + (w0 - 1);
  const float* xb = x + ((size_t)(b * CIN + c8 * 8)) * (HH * WW);
  f32x4 v[8];
#pragma unroll
  for (int j = 0; j < 8; j++) v[j] = *(const f32x4*)(xb + j * (HH * WW) + base);

  // ---- mini-MLP: 8 dots of 256 (coalesced w2 column reads + butterfly reduce)
  float tv = t1[b * CIN + tid];
  float pj[8];
#pragma unroll
  for (int j = 0; j < 8; j++) pj[j] = w2[(size_t)(c8 * 8 + j) * CIN + tid] * tv;
#pragma unroll
  for (int off = 32; off; off >>= 1)
#pragma unroll
    for (int j = 0; j < 8; j++) pj[j] += __shfl_xor(pj[j], off, 64);
  __shared__ float red[4][8];
  __shared__ float sv_sh[8];
  if (lane == 0)
#pragma unroll
    for (int j = 0; j < 8; j++) red[wid][j] = pj[j];
  __syncthreads();
  if (tid < 8) {
    float a = red[0][tid] + red[1][tid] + red[2][tid] + red[3][tid] + b2[c8 * 8 + tid];
    sv_sh[tid] = a >= 0.f ? a : 0.01f * a;
  }
  __syncthreads();
  float sv[8];
#pragma unroll
  for (int j = 0; j < 8; j++) sv[j] = sv_sh[j];

  unsigned short* xp = xpad + ((size_t)(b * 32 + c8)) * PLANE;

  // ---- zero border: quarter q handles 65 of the 260 border cells
  if (tid < 65) {
    int i = q * 65 + tid;
    int bh, bw;
    if (i < 66) { bh = 0; bw = i; }
    else if (i < 132) { bh = 65; bw = i - 66; }
    else if (i < 196) { bh = i - 132 + 1; bw = 0; }
    else { bh = i - 196 + 1; bw = 65; }
    ushort8 z = {0, 0, 0, 0, 0, 0, 0, 0};
    *(ushort8*)(xp + (bh * WP + bw) * 8) = z;
  }

  // ---- convert + store (4 px x 8 ch = 64B contiguous per thread)
  unsigned short* op = xp + (hh * WP + w0) * 8;
#pragma unroll
  for (int t2 = 0; t2 < 4; t2++) {
    ushort8 o;
#pragma unroll
    for (int j = 0; j < 8; j++) o[j] = f2bf(v[j][t2] * sv[j]);
    *(ushort8*)(op + t2 * 8) = o;
  }
}

// ---------------- implicit-GEMM conv: BM=128 px, BN=256 out, BK=64
__device__ __forceinline__ void gl2lds16(const void* g, void* l) {
  __builtin_amdgcn_global_load_lds((const __attribute__((address_space(1))) void*)g,
                                   (__attribute__((address_space(3))) void*)l, 16, 0, 0);
}

__global__ void __launch_bounds__(512, 4) gemm_conv(const unsigned short* __restrict__ xpad,
                                                    const unsigned short* __restrict__ wt,
                                                    float* __restrict__ out) {
  __shared__ unsigned short As[128 * 64];  // [pixel][64ch], 128B rows, XOR-swizzled chunks
  __shared__ unsigned short Bs[256 * 64];  // [o][64ch]
  int tid = threadIdx.x;
  int wid = tid >> 6, lane = tid & 63;
  int bid = blockIdx.x;
  // XCD swizzle (%8 round-robin heuristic): XCD x covers m_t in [x*64, x*64+64)
  // = 2 contiguous images -> A footprint ~4.5 MB ~= one XCD L2.
  int m_t = (bid & 7) * 64 + (bid >> 3);
  int m0 = m_t << 7;
  int b = m0 >> 12;
  int h0 = (m0 >> 6) & 63;           // tile covers image rows h0, h0+1
  int wm = wid & 1, wn = wid >> 1;   // 2x4 wave grid, each wave 64x64

  f32x4 acc[4][4];
#pragma unroll
  for (int mi = 0; mi < 4; mi++)
#pragma unroll
    for (int ni = 0; ni < 4; ni++) acc[mi][ni] = (f32x4){0.f, 0.f, 0.f, 0.f};

  // ---- stager lane invariants (global lane id = tid)
  int p = tid >> 3;                  // pixel 0..63 (round 1: +64 -> next image row)
  int cs = tid & 7;                  // chunk slot in LDS row
  int gsA = cs ^ (p & 7);            // XOR swizzle: LDS slot cs holds global chunk gsA
  const unsigned short* aL =
      xpad + ((size_t)((b * 32 + gsA) * HP + h0)) * (WP * 8) + p * 8;
  int o_l = tid >> 3;                // o 0..63 within a 64-row round
  const unsigned short* bL = wt + o_l * CIN + (cs ^ (o_l & 7)) * 8;

  char* As_w0 = (char*)As + wid * 1024;
  char* As_w1 = (char*)As + 8192 + wid * 1024;
  char* Bs_w0 = (char*)Bs + wid * 1024;
  char* Bs_w1 = (char*)Bs + 8192 + wid * 1024;
  char* Bs_w2 = (char*)Bs + 16384 + wid * 1024;
  char* Bs_w3 = (char*)Bs + 24576 + wid * 1024;

  // ---- reader frag offsets (bytes into As/Bs), XOR-unswizzled
  int rA = wm * 64 + (lane & 15);
  int rB = wn * 64 + (lane & 15);
  int qa = lane >> 4;
  int offA0 = rA * 128 + ((qa ^ (rA & 7)) * 16);
  int offA1 = rA * 128 + (((qa + 4) ^ (rA & 7)) * 16);
  int offB0 = rB * 128 + ((qa ^ (rB & 7)) * 16);
  int offB1 = rB * 128 + (((qa + 4) ^ (rB & 7)) * 16);

  for (int kh = 0; kh < 3; kh++) {
    for (int kw = 0; kw < 3; kw++) {
      const unsigned short* aT = aL + (kh * WP + kw) * 8;
      const unsigned short* bT = bL + (kh * 3 + kw) * (COUT * CIN);
#pragma unroll
      for (int kc2 = 0; kc2 < 4; kc2++) {
        const unsigned short* aG = aT + kc2 * (8 * PLANE);
        const unsigned short* bG = bT + kc2 * 64;
        gl2lds16(aG, As_w0);
        gl2lds16(aG + WP * 8, As_w1);
        gl2lds16(bG, Bs_w0);
        gl2lds16(bG + 64 * CIN, Bs_w1);
        gl2lds16(bG + 128 * CIN, Bs_w2);
        gl2lds16(bG + 192 * CIN, Bs_w3);
        __syncthreads();
#pragma unroll
        for (int kb = 0; kb < 2; kb++) {
          int oa = kb ? offA1 : offA0;
          int ob = kb ? offB1 : offB0;
          bf16x8 av[4], bv[4];
#pragma unroll
          for (int mi = 0; mi < 4; mi++)
            av[mi] = *(const bf16x8*)((const char*)As + oa + mi * 2048);
#pragma unroll
          for (int ni = 0; ni < 4; ni++)
            bv[ni] = *(const bf16x8*)((const char*)Bs + ob + ni * 2048);
#pragma unroll
          for (int mi = 0; mi < 4; mi++)
#pragma unroll
            for (int ni = 0; ni < 4; ni++)
              acc[mi][ni] = __builtin_amdgcn_mfma_f32_16x16x32_bf16(av[mi], bv[ni],
                                                                    acc[mi][ni], 0, 0, 0);
        }
        __syncthreads();
      }
    }
  }

  // ---- epilogue: D row = pixel (quad*4+reg), col = o (lane&15)
  int pixbase = m0 & 4095;
  int quad = lane >> 4;
  int col = lane & 15;
#pragma unroll
  for (int mi = 0; mi < 4; mi++) {
    int pm = pixbase + wm * 64 + mi * 16 + quad * 4;
#pragma unroll
    for (int ni = 0; ni < 4; ni++) {
      int on = wn * 64 + ni * 16 + col;
      float* op = out + ((size_t)(b * COUT + on) << 12) + pm;
      *(f32x4*)op = acc[mi][ni];
    }
  }
}

extern "C" void kernel_launch(void* const* d_in, const int* in_sizes, int n_in,
                              void* d_out, int out_size, void* d_ws, size_t ws_size,
                              hipStream_t stream) {
  const float* x = (const float*)d_in[0];
  const float* y = (const float*)d_in[1];
  const float* w0 = (const float*)d_in[2];
  const float* b0 = (const float*)d_in[3];
  const float* w1 = (const float*)d_in[4];
  const float* b1 = (const float*)d_in[5];
  const float* w2 = (const float*)d_in[6];
  const float* b2 = (const float*)d_in[7];
  const float* cw = (const float*)d_in[8];
  float* out = (float*)d_out;

  // workspace: t0 | t1 | wt bf16 | xpad bf16
  char* ws = (char*)d_ws;
  float* t0 = (float*)ws;                       // 16 KiB
  float* t1 = (float*)(ws + 16384);             // 16 KiB
  unsigned short* wt = (unsigned short*)(ws + 32768);  // 1.125 MiB
  unsigned short* xpad = (unsigned short*)(ws + 32768 + 9 * COUT * CIN * 2);

  mlp_layer<DCAT><<<BATCH * CIN / 4, 256, 0, stream>>>(y, w0, b0, t0);
  mlp_layer<CIN><<<BATCH * CIN / 4, 256, 0, stream>>>(t0, w1, b1, t1);
  prep_w<<<9 * COUT * CIN / 4 / 256, 256, 0, stream>>>(cw, wt);
  mlp3_prep_x<<<BATCH * 32 * 4, 256, 0, stream>>>(t1, w2, b2, x, xpad);
  gemm_conv<<<BATCH * HH * WW / 128, 512, 0, stream>>>(xpad, wt, out);
}